// Round 11
// baseline (1223.057 us; speedup 1.0000x reference)
//
#include <hip/hip_runtime.h>
#include <hip/hip_bf16.h>

typedef __bf16 bf16x8 __attribute__((ext_vector_type(8)));
typedef float  f32x4  __attribute__((ext_vector_type(4)));

#define BM 256
#define BN 256
#define BK 64
#define THREADS 512

__device__ __forceinline__ void gload_lds16(const void* g, void* l) {
  __builtin_amdgcn_global_load_lds(
      (const __attribute__((address_space(1))) void*)g,
      (__attribute__((address_space(3))) void*)l, 16, 0, 0);
}

// Bare counted waits (round-6 lesson: ":::memory" clobber => conservative
// vmcnt(0) drain). Ordering vs C++ code pinned with sched_barrier(0).
template<int N> __device__ __forceinline__ void vmwait() {
  if constexpr (N == 0)      asm volatile("s_waitcnt vmcnt(0)");
  else if constexpr (N == 8) asm volatile("s_waitcnt vmcnt(8)");
}

__device__ __forceinline__ void tile_barrier() {
  __builtin_amdgcn_sched_barrier(0);
  asm volatile("s_barrier");
  __builtin_amdgcn_sched_barrier(0);
}

// ---- fp32 -> bf16 (RNE) ----
__global__ void cvt_x_kernel(const float* __restrict__ in, __bf16* __restrict__ out, long n) {
  long i0 = ((long)blockIdx.x * blockDim.x + threadIdx.x) * 8;
  long stride = (long)gridDim.x * blockDim.x * 8;
  for (long i = i0; i < n; i += stride) {
    float4 f0 = *(const float4*)(in + i);
    float4 f1 = *(const float4*)(in + i + 4);
    bf16x8 v;
    v[0] = (__bf16)f0.x; v[1] = (__bf16)f0.y; v[2] = (__bf16)f0.z; v[3] = (__bf16)f0.w;
    v[4] = (__bf16)f1.x; v[5] = (__bf16)f1.y; v[6] = (__bf16)f1.z; v[7] = (__bf16)f1.w;
    *(bf16x8*)(out + i) = v;
  }
}

// ---- (int32 weight - zp) -> bf16, EXACT for |v|<=255 ----
__global__ void cvt_w_kernel(const int* __restrict__ w, const int* __restrict__ zp,
                             __bf16* __restrict__ out, int K, long n) {
  long i0 = ((long)blockIdx.x * blockDim.x + threadIdx.x) * 8;
  long stride = (long)gridDim.x * blockDim.x * 8;
  for (long i = i0; i < n; i += stride) {
    int4 a = *(const int4*)(w + i);
    int4 b = *(const int4*)(w + i + 4);
    int z = zp[i / K];
    bf16x8 v;
    v[0] = (__bf16)(float)(a.x - z); v[1] = (__bf16)(float)(a.y - z);
    v[2] = (__bf16)(float)(a.z - z); v[3] = (__bf16)(float)(a.w - z);
    v[4] = (__bf16)(float)(b.x - z); v[5] = (__bf16)(float)(b.y - z);
    v[6] = (__bf16)(float)(b.z - z); v[7] = (__bf16)(float)(b.w - z);
    *(bf16x8*)(out + i) = v;
  }
}

// ====== 256x256 GEMM: one region/K-tile, fragment-granular pipeline ======
// Round-10 ledger: 5578 cy/tile = MFMA 2483 + ds_read 2304 + ds_write 512 +
// sync ~280 -> pipes fully SERIAL. Cause: program order [4 reads; 16 MFMA]x4
// forces a near-drain lgkmcnt before each MFMA cluster and the scheduler does
// not hoist next-quadrant reads over MFMAs. Fix: explicit per-fragment
// pipeline IN PROGRAM ORDER:
//   bf x8; af(0); for f=0..15: { read af(f+1) ; 4 MFMAs using af(f) }
// Each ds_read (12 cy) hides under 4 MFMAs; lgkmcnt is counted (1), never 0.
// af ping-pong = 2 live frags (8 VGPR, was 16).
// Sync/staging identical to round 10:
//   tile_barrier (i); 8x gload_lds t+2 -> buf b; vmcnt(8); tile_barrier (ii)
// RAW: batches are exactly 8 loads/tile/wave in tile order; at vmcnt(8),
// outstanding = t+1's 8 + t+2's 8 -> retires t+1 exactly. WAR: every ds_read
// feeds an MFMA above barrier (i) -> data-dep lgkmcnt completes them.
// Tails peeled branch-free (round-5 spill lesson).
__global__ __launch_bounds__(THREADS, 2)
void qlin_gemm(const __bf16* __restrict__ A, const __bf16* __restrict__ B,
               const float* __restrict__ scale, const float* __restrict__ bias,
               float* __restrict__ C, int M, int N, int K) {
  __shared__ alignas(16) __bf16 As[2][BM * BK];
  __shared__ alignas(16) __bf16 Bs[2][BN * BK];

  const int tid  = threadIdx.x;
  const int wave = tid >> 6;
  const int lane = tid & 63;
  const int wm = wave >> 2, wn = wave & 3;       // 2x4 waves; per-wave 128x64

  int bid = blockIdx.x, nwg = gridDim.x, swz = bid;
  if ((nwg & 7) == 0) swz = (bid & 7) * (nwg >> 3) + (bid >> 3);
  const int ntn = N / BN;
  const long row0 = (long)(swz / ntn) * BM;
  const long col0 = (long)(swz % ntn) * BN;

  const __bf16* Ag = A + row0 * (long)K;
  const __bf16* Bg = B + col0 * (long)K;

  // staging: chunk c = rows [c*64, c*64+64); wave-uniform LDS base; HW adds lane*16B
  const int srow = wave * 8 + (lane >> 3);            // row within chunk
  const int kswz = ((lane & 7) ^ (lane >> 3)) * 8;    // pre-swizzled k elems (T2)

#define STAGE_A(b, c, kt) gload_lds16(Ag + (long)((c)*64 + srow) * K + (kt) + kswz, \
                                      &As[b][(c)*4096 + wave*512])
#define STAGE_B(b, c, kt) gload_lds16(Bg + (long)((c)*64 + srow) * K + (kt) + kswz, \
                                      &Bs[b][(c)*4096 + wave*512])
#define STAGE8(b, kt) { STAGE_B(b,0,kt); STAGE_B(b,1,kt); STAGE_B(b,2,kt); STAGE_B(b,3,kt); \
                        STAGE_A(b,0,kt); STAGE_A(b,1,kt); STAGE_A(b,2,kt); STAGE_A(b,3,kt); }

  const int rsel = lane & 15;
  const int ksl  = lane >> 4;    // 0..3
  const int lan7 = lane & 7;     // == frag-row & 7 (bases are multiples of 16)

  f32x4  acc[8][4] = {};
  bf16x8 bf[4][2];               // B frags [n][kk], live across one tile

#define AF_READ(bb, m, kk)                                                      \
  (*(const bf16x8*)&As[bb][(wm*128 + (m)*16 + rsel)*BK                          \
                           + (((((kk)<<2)+ksl) ^ lan7) << 3)])

#define TILE(bb, STAGES, ENDW)                                                   \
  {                                                                              \
    __builtin_amdgcn_s_setprio(1);                                               \
    _Pragma("unroll")                                                            \
    for (int n = 0; n < 4; ++n)                                                  \
      _Pragma("unroll")                                                          \
      for (int kk = 0; kk < 2; ++kk)                                             \
        bf[n][kk] = *(const bf16x8*)&Bs[bb][(wn*64 + n*16 + rsel)*BK             \
                                            + ((((kk<<2)+ksl) ^ lan7) << 3)];    \
    bf16x8 afp0, afp1;                                                           \
    afp0 = AF_READ(bb, 0, 0);                                                    \
    _Pragma("unroll")                                                            \
    for (int f = 0; f < 16; ++f) {                                               \
      const int m = f & 7, kk = f >> 3;                                          \
      if (f < 15) {                                                              \
        const int m2 = (f + 1) & 7, kk2 = (f + 1) >> 3;                          \
        if (f & 1) afp0 = AF_READ(bb, m2, kk2);                                  \
        else       afp1 = AF_READ(bb, m2, kk2);                                  \
      }                                                                          \
      _Pragma("unroll")                                                          \
      for (int n = 0; n < 4; ++n)                                                \
        acc[m][n] = __builtin_amdgcn_mfma_f32_16x16x32_bf16(                     \
            (f & 1) ? afp1 : afp0, bf[n][kk], acc[m][n], 0, 0, 0);               \
    }                                                                            \
    __builtin_amdgcn_s_setprio(0);                                               \
    tile_barrier();  /* (i) */                                                   \
    STAGES;                                                                      \
    ENDW;                                                                        \
    tile_barrier();  /* (ii) */                                                  \
  }

  const int NT = K / BK;   // even, >= 6 (guarded by launcher)

  // Prologue: stage tile0 -> buf0, tile1 -> buf1; land tile0 before entering.
  STAGE8(0, 0)
  STAGE8(1, BK)
  vmwait<8>();                       // tile0's 8 retired; tile1's 8 in flight
  tile_barrier();

  // Steady: pairs (t, t+1), literal bufs (0,1); tile t stages t+2.
  for (int t = 0; t < NT - 3; t += 2) {
    const long kt2 = (long)(t + 2) * BK;
    const long kt3 = (long)(t + 3) * BK;
    TILE(0, STAGE8(0, kt2), vmwait<8>())
    TILE(1, STAGE8(1, kt3), vmwait<8>())
  }
  TILE(0, (void)0, vmwait<0>())      // tile NT-2: drain tile NT-1's batch
  TILE(1, (void)0, (void)0)          // tile NT-1: pure compute
#undef TILE
#undef AF_READ
#undef STAGE8
#undef STAGE_A
#undef STAGE_B

  // Epilogue. C/D: col = lane&15, row = (lane>>4)*4 + j
  float sc[4], bv[4];
  #pragma unroll
  for (int n = 0; n < 4; ++n) {
    const long gcol = col0 + wn * 64 + n * 16 + rsel;
    sc[n] = scale[gcol];
    bv[n] = bias[gcol];
  }
  #pragma unroll
  for (int m = 0; m < 8; ++m) {
    const long grow = row0 + wm * 128 + m * 16 + ksl * 4;
    #pragma unroll
    for (int n = 0; n < 4; ++n) {
      const long gcol = col0 + wn * 64 + n * 16 + rsel;
      float* o = C + grow * (long)N + gcol;
      #pragma unroll
      for (int j = 0; j < 4; ++j)
        o[(long)j * N] = acc[m][n][j] * sc[n] + bv[n];
    }
  }
}

// ---- fallback (ws too small / odd shape): reg-staged 128x128, inline dequant ----
__global__ __launch_bounds__(256)
void qlin_gemm_small(const float* __restrict__ Af, const int* __restrict__ Bi,
                     const int* __restrict__ zp,
                     const float* __restrict__ scale, const float* __restrict__ bias,
                     float* __restrict__ C, int M, int N, int K) {
  __shared__ alignas(16) __bf16 As[128 * 64];
  __shared__ alignas(16) __bf16 Bs[128 * 64];
  const int tid = threadIdx.x, wave = tid >> 6, lane = tid & 63;
  int bid = blockIdx.x, nwg = gridDim.x, swz = bid;
  if ((nwg & 7) == 0) swz = (bid & 7) * (nwg >> 3) + (bid >> 3);
  const int ntn = N / 128;
  const long row0 = (long)(swz / ntn) * 128, col0 = (long)(swz % ntn) * 128;
  const int wr = wave >> 1, wc = wave & 1;
  f32x4 acc[4][4] = {};
  for (int kt = 0; kt < K; kt += 64) {
    #pragma unroll
    for (int i = 0; i < 4; ++i) {
      const int flat = i * 2048 + tid * 8;
      const int r = flat >> 6, cc = flat & 63;
      const int wcc = ((cc >> 3) ^ (r & 7)) << 3;
      const float* g = Af + (row0 + r) * (long)K + kt + cc;
      float4 f0 = *(const float4*)g; float4 f1 = *(const float4*)(g + 4);
      bf16x8 v;
      v[0]=(__bf16)f0.x; v[1]=(__bf16)f0.y; v[2]=(__bf16)f0.z; v[3]=(__bf16)f0.w;
      v[4]=(__bf16)f1.x; v[5]=(__bf16)f1.y; v[6]=(__bf16)f1.z; v[7]=(__bf16)f1.w;
      *(bf16x8*)(As + r * 64 + wcc) = v;
    }
    #pragma unroll
    for (int i = 0; i < 4; ++i) {
      const int flat = i * 2048 + tid * 8;
      const int r = flat >> 6, cc = flat & 63;
      const int wcc = ((cc >> 3) ^ (r & 7)) << 3;
      const long grow = col0 + r;
      const int z = zp[grow];
      const int* g = Bi + grow * (long)K + kt + cc;
      int4 a = *(const int4*)g; int4 b = *(const int4*)(g + 4);
      bf16x8 v;
      v[0]=(__bf16)(float)(a.x-z); v[1]=(__bf16)(float)(a.y-z);
      v[2]=(__bf16)(float)(a.z-z); v[3]=(__bf16)(float)(a.w-z);
      v[4]=(__bf16)(float)(b.x-z); v[5]=(__bf16)(float)(b.y-z);
      v[6]=(__bf16)(float)(b.z-z); v[7]=(__bf16)(float)(b.w-z);
      *(bf16x8*)(Bs + r * 64 + wcc) = v;
    }
    __syncthreads();
    #pragma unroll
    for (int kk = 0; kk < 2; ++kk) {
      bf16x8 af[4], bfr[4];
      const int rs = lane & 15, ks = kk * 4 + (lane >> 4);
      const int rd = (ks ^ (lane & 7)) << 3;
      #pragma unroll
      for (int m = 0; m < 4; ++m) af[m] = *(const bf16x8*)(As + (wr*64 + m*16 + rs)*64 + rd);
      #pragma unroll
      for (int n = 0; n < 4; ++n) bfr[n] = *(const bf16x8*)(Bs + (wc*64 + n*16 + rs)*64 + rd);
      #pragma unroll
      for (int m = 0; m < 4; ++m)
        #pragma unroll
        for (int n = 0; n < 4; ++n)
          acc[m][n] = __builtin_amdgcn_mfma_f32_16x16x32_bf16(af[m], bfr[n], acc[m][n], 0, 0, 0);
    }
    __syncthreads();
  }
  #pragma unroll
  for (int m = 0; m < 4; ++m) {
    const long grow = row0 + wr * 64 + m * 16 + ((lane >> 4) << 2);
    #pragma unroll
    for (int n = 0; n < 4; ++n) {
      const long gcol = col0 + wc * 64 + n * 16 + (lane & 15);
      const float s = scale[gcol], bb2 = bias[gcol];
      float* o = C + grow * (long)N + gcol;
      #pragma unroll
      for (int j = 0; j < 4; ++j) o[(long)j * N] = acc[m][n][j] * s + bb2;
    }
  }
}

extern "C" void kernel_launch(void* const* d_in, const int* in_sizes, int n_in,
                              void* d_out, int out_size, void* d_ws, size_t ws_size,
                              hipStream_t stream) {
  const float* x    = (const float*)d_in[0];
  const int*   wint = (const int*)d_in[1];
  const float* wsc  = (const float*)d_in[2];
  const int*   wzp  = (const int*)d_in[3];
  const float* bias = (const float*)d_in[4];
  float* out = (float*)d_out;

  const int N = in_sizes[4];            // 16384 (OUT)
  const int K = in_sizes[1] / N;        // 4096  (IN)
  const int M = in_sizes[0] / K;        // 8192  (B*S)

  const size_t xbytes = (size_t)M * K * sizeof(__bf16);
  const size_t wbytes = (size_t)N * K * sizeof(__bf16);
  const int NT = K / BK;

  if (ws_size >= xbytes + wbytes && (M % BM) == 0 && (N % BN) == 0 &&
      (K % BK) == 0 && NT >= 6 && (NT % 2) == 0) {
    __bf16* xb = (__bf16*)d_ws;
    __bf16* wb = (__bf16*)((char*)d_ws + xbytes);
    cvt_x_kernel<<<2048, 256, 0, stream>>>(x, xb, (long)M * K);
    cvt_w_kernel<<<2048, 256, 0, stream>>>(wint, wzp, wb, K, (long)N * K);
    const int grid = (M / BM) * (N / BN); // 32 * 64 = 2048
    qlin_gemm<<<grid, THREADS, 0, stream>>>(xb, wb, wsc, bias, out, M, N, K);
  } else {
    const int grid = (M / 128) * (N / 128);
    qlin_gemm_small<<<grid, 256, 0, stream>>>(x, wint, wzp, wsc, bias, out, M, N, K);
  }
}

// Round 12
// 715.110 us; speedup vs baseline: 1.7103x; 1.7103x over previous
//
#include <hip/hip_runtime.h>
#include <hip/hip_bf16.h>

typedef __bf16 bf16x8 __attribute__((ext_vector_type(8)));
typedef float  f32x4  __attribute__((ext_vector_type(4)));
typedef int    i32x4  __attribute__((ext_vector_type(4)));

#define BM 256
#define BN 256
#define BK 128          // int8 K-tile; rows are 128 B -> same swizzle as bf16
#define THREADS 512

__device__ __forceinline__ void gload_lds16(const void* g, void* l) {
  __builtin_amdgcn_global_load_lds(
      (const __attribute__((address_space(1))) void*)g,
      (__attribute__((address_space(3))) void*)l, 16, 0, 0);
}

// Bare counted waits (round-6 lesson: ":::memory" clobber => conservative
// vmcnt(0) drain). Ordering vs C++ code pinned with sched_barrier(0).
template<int N> __device__ __forceinline__ void vmwait() {
  if constexpr (N == 0)      asm volatile("s_waitcnt vmcnt(0)");
  else if constexpr (N == 8) asm volatile("s_waitcnt vmcnt(8)");
}

__device__ __forceinline__ void tile_barrier() {
  __builtin_amdgcn_sched_barrier(0);
  asm volatile("s_barrier");
  __builtin_amdgcn_sched_barrier(0);
}

// ---- per-row x quantization: sx = rowmax/127, q = rne(x/sx), rowsum = sum q ----
__global__ __launch_bounds__(256)
void quant_x(const float* __restrict__ x, signed char* __restrict__ xq,
             float* __restrict__ sx, int* __restrict__ rowsum, int K) {
  const int row = blockIdx.x, tid = threadIdx.x;
  const int wave = tid >> 6, lane = tid & 63;
  const float* xr = x + (long)row * K;
  __shared__ float smax[4];
  __shared__ int   ssum[4];

  float amax = 0.f;
  for (int i = tid * 16; i < K; i += 256 * 16) {
    #pragma unroll
    for (int j = 0; j < 4; ++j) {
      float4 v = *(const float4*)(xr + i + j * 4);
      amax = fmaxf(amax, fmaxf(fmaxf(fabsf(v.x), fabsf(v.y)),
                               fmaxf(fabsf(v.z), fabsf(v.w))));
    }
  }
  #pragma unroll
  for (int m = 32; m >= 1; m >>= 1) amax = fmaxf(amax, __shfl_xor(amax, m));
  if (lane == 0) smax[wave] = amax;
  __syncthreads();
  const float m4 = fmaxf(fmaxf(smax[0], smax[1]), fmaxf(smax[2], smax[3]));
  const float scale = (m4 > 0.f) ? (m4 / 127.f) : 1.f;
  const float inv   = (m4 > 0.f) ? (127.f / m4) : 0.f;

  int lsum = 0;
  for (int i = tid * 16; i < K; i += 256 * 16) {
    union { signed char c[16]; int4 v; } u;
    #pragma unroll
    for (int j = 0; j < 4; ++j) {
      float4 v = *(const float4*)(xr + i + j * 4);
      int q0 = __float2int_rn(v.x * inv), q1 = __float2int_rn(v.y * inv);
      int q2 = __float2int_rn(v.z * inv), q3 = __float2int_rn(v.w * inv);
      u.c[j*4+0] = (signed char)q0; u.c[j*4+1] = (signed char)q1;
      u.c[j*4+2] = (signed char)q2; u.c[j*4+3] = (signed char)q3;
      lsum += q0 + q1 + q2 + q3;
    }
    *(int4*)(xq + (long)row * K + i) = u.v;
  }
  #pragma unroll
  for (int m = 32; m >= 1; m >>= 1) lsum += __shfl_xor(lsum, m);
  if (lane == 0) ssum[wave] = lsum;
  __syncthreads();
  if (tid == 0) {
    rowsum[row] = ssum[0] + ssum[1] + ssum[2] + ssum[3];
    sx[row] = scale;
  }
}

// ---- (int32 weight - zp) -> int8 (exact for the symmetric-quant data) ----
__global__ void conv_w(const int* __restrict__ w, const int* __restrict__ zp,
                       signed char* __restrict__ wq, int K, long n) {
  long i0 = ((long)blockIdx.x * blockDim.x + threadIdx.x) * 16;
  long stride = (long)gridDim.x * blockDim.x * 16;
  for (long i = i0; i < n; i += stride) {
    const int z = zp[i / K];
    union { signed char c[16]; int4 v; } u;
    #pragma unroll
    for (int j = 0; j < 4; ++j) {
      int4 a = *(const int4*)(w + i + j * 4);
      int q0 = min(127, max(-128, a.x - z)), q1 = min(127, max(-128, a.y - z));
      int q2 = min(127, max(-128, a.z - z)), q3 = min(127, max(-128, a.w - z));
      u.c[j*4+0] = (signed char)q0; u.c[j*4+1] = (signed char)q1;
      u.c[j*4+2] = (signed char)q2; u.c[j*4+3] = (signed char)q3;
    }
    *(int4*)(wq + i) = u.v;
  }
}

// ====== int8 256x256 GEMM, BK=128, r10 skeleton (one region/K-tile) ======
// Per-tile instruction mix identical to the bf16 r10 tile (8 stage-loads,
// 24 ds_read_b128, 64 MFMAs per wave) but each MFMA is 16x16x64_i8 (2x FLOP)
// and each K-tile covers K=128 -> NT halves to 32. Rows are 128 B -> XOR-8
// swizzle carried over unchanged (slot' = slot ^ (row&7), 16B slots).
// Sync per tile: tile_barrier(i); 8x gload_lds t+2 -> buf b; vmcnt(8);
// tile_barrier(ii). RAW/WAR identical to r10. Tails peeled branch-free.
// Epilogue: out = sx[r]*sw[c]*(acc - zp[c]*rowsum[r]) + bias[c]  (zp exact).
__global__ __launch_bounds__(THREADS, 2)
void qlin_gemm_i8(const signed char* __restrict__ A, const signed char* __restrict__ B,
                  const float* __restrict__ sx, const int* __restrict__ rowsum,
                  const int* __restrict__ zp,
                  const float* __restrict__ scale, const float* __restrict__ bias,
                  float* __restrict__ C, int M, int N, int K) {
  __shared__ alignas(16) signed char As[2][BM * BK];   // 2 x 32 KiB
  __shared__ alignas(16) signed char Bs[2][BN * BK];   // 2 x 32 KiB

  const int tid  = threadIdx.x;
  const int wave = tid >> 6;
  const int lane = tid & 63;
  const int wm = wave >> 2, wn = wave & 3;       // 2x4 waves; per-wave 128x64

  int bid = blockIdx.x, nwg = gridDim.x, swz = bid;
  if ((nwg & 7) == 0) swz = (bid & 7) * (nwg >> 3) + (bid >> 3);
  const int ntn = N / BN;
  const long row0 = (long)(swz / ntn) * BM;
  const long col0 = (long)(swz % ntn) * BN;

  const signed char* Ag = A + row0 * (long)K;
  const signed char* Bg = B + col0 * (long)K;

  // staging: instr covers 8 rows x 128 B; lane l -> row +(l>>3), 16B slot l&7.
  // Pre-swizzled source slot = (l&7) ^ (l>>3)  (same involution as the read).
  const int srow = wave * 8 + (lane >> 3);
  const int kswz = ((lane & 7) ^ (lane >> 3)) * 16;   // bytes == int8 elems

#define STAGE_A(b, c, kt) gload_lds16(Ag + (long)((c)*64 + srow) * K + (kt) + kswz, \
                                      &As[b][(c)*8192 + wave*1024])
#define STAGE_B(b, c, kt) gload_lds16(Bg + (long)((c)*64 + srow) * K + (kt) + kswz, \
                                      &Bs[b][(c)*8192 + wave*1024])
#define STAGE8(b, kt) { STAGE_B(b,0,kt); STAGE_B(b,1,kt); STAGE_B(b,2,kt); STAGE_B(b,3,kt); \
                        STAGE_A(b,0,kt); STAGE_A(b,1,kt); STAGE_A(b,2,kt); STAGE_A(b,3,kt); }

  const int rsel = lane & 15;     // fragment row
  const int ksl  = lane >> 4;     // 0..3 -> k-offset = ksl*16 within K=64 block
  const int lan7 = lane & 7;      // == frag-row & 7 (bases are multiples of 16)

  i32x4 acc[8][4] = {};
  i32x4 bf[4][2];                 // B frags [n][kk], live across one tile

#define AF_READ(bb, m, kk)                                                      \
  (*(const i32x4*)&As[bb][(wm*128 + (m)*16 + rsel)*BK                           \
                          + (((((kk)<<2)+ksl) ^ lan7) << 4)])

#define TILE(bb, STAGES, ENDW)                                                   \
  {                                                                              \
    __builtin_amdgcn_s_setprio(1);                                               \
    _Pragma("unroll")                                                            \
    for (int n = 0; n < 4; ++n)                                                  \
      _Pragma("unroll")                                                          \
      for (int kk = 0; kk < 2; ++kk)                                             \
        bf[n][kk] = *(const i32x4*)&Bs[bb][(wn*64 + n*16 + rsel)*BK              \
                                           + ((((kk<<2)+ksl) ^ lan7) << 4)];     \
    i32x4 afp0, afp1;                                                            \
    afp0 = AF_READ(bb, 0, 0);                                                    \
    _Pragma("unroll")                                                            \
    for (int f = 0; f < 16; ++f) {                                               \
      const int m = f & 7, kk = f >> 3;                                          \
      if (f < 15) {                                                              \
        const int m2 = (f + 1) & 7, kk2 = (f + 1) >> 3;                          \
        if (f & 1) afp0 = AF_READ(bb, m2, kk2);                                  \
        else       afp1 = AF_READ(bb, m2, kk2);                                  \
      }                                                                          \
      _Pragma("unroll")                                                          \
      for (int n = 0; n < 4; ++n)                                                \
        acc[m][n] = __builtin_amdgcn_mfma_i32_16x16x64_i8(                       \
            (f & 1) ? afp1 : afp0, bf[n][kk], acc[m][n], 0, 0, 0);               \
    }                                                                            \
    __builtin_amdgcn_s_setprio(0);                                               \
    tile_barrier();  /* (i) */                                                   \
    STAGES;                                                                      \
    ENDW;                                                                        \
    tile_barrier();  /* (ii) */                                                  \
  }

  const int NT = K / BK;   // 32 for this shape; even, >= 6 (guarded)

  // Prologue: stage tile0 -> buf0, tile1 -> buf1; land tile0 before entering.
  STAGE8(0, 0)
  STAGE8(1, BK)
  vmwait<8>();
  tile_barrier();

  for (int t = 0; t < NT - 3; t += 2) {
    const long kt2 = (long)(t + 2) * BK;
    const long kt3 = (long)(t + 3) * BK;
    TILE(0, STAGE8(0, kt2), vmwait<8>())
    TILE(1, STAGE8(1, kt3), vmwait<8>())
  }
  TILE(0, (void)0, vmwait<0>())      // tile NT-2: drain tile NT-1's batch
  TILE(1, (void)0, (void)0)          // tile NT-1: pure compute
#undef TILE
#undef AF_READ
#undef STAGE8
#undef STAGE_A
#undef STAGE_B

  // Epilogue. C/D layout (dtype-independent, m121-128): col = lane&15,
  // row = (lane>>4)*4 + j.  out = sx*sw*(acc - zp*rowsum) + bias.
  float swv[4], bvv[4]; int zpv[4];
  #pragma unroll
  for (int n = 0; n < 4; ++n) {
    const long gcol = col0 + wn * 64 + n * 16 + rsel;
    swv[n] = scale[gcol];
    bvv[n] = bias[gcol];
    zpv[n] = zp[gcol];
  }
  #pragma unroll
  for (int m = 0; m < 8; ++m) {
    const long growb = row0 + wm * 128 + m * 16 + ksl * 4;
    #pragma unroll
    for (int j = 0; j < 4; ++j) {
      const long grow = growb + j;
      const float sxv = sx[grow];
      const int   rsv = rowsum[grow];
      float* orow = C + grow * (long)N;
      #pragma unroll
      for (int n = 0; n < 4; ++n) {
        const long gcol = col0 + wn * 64 + n * 16 + rsel;
        orow[gcol] = (float)(acc[m][n][j] - zpv[n] * rsv) * (sxv * swv[n]) + bvv[n];
      }
    }
  }
}

// ---- fallback (ws too small / odd shape): reg-staged 128x128 bf16, inline dequant ----
__global__ __launch_bounds__(256)
void qlin_gemm_small(const float* __restrict__ Af, const int* __restrict__ Bi,
                     const int* __restrict__ zp,
                     const float* __restrict__ scale, const float* __restrict__ bias,
                     float* __restrict__ C, int M, int N, int K) {
  __shared__ alignas(16) __bf16 As[128 * 64];
  __shared__ alignas(16) __bf16 Bs[128 * 64];
  const int tid = threadIdx.x, wave = tid >> 6, lane = tid & 63;
  int bid = blockIdx.x, nwg = gridDim.x, swz = bid;
  if ((nwg & 7) == 0) swz = (bid & 7) * (nwg >> 3) + (bid >> 3);
  const int ntn = N / 128;
  const long row0 = (long)(swz / ntn) * 128, col0 = (long)(swz % ntn) * 128;
  const int wr = wave >> 1, wc = wave & 1;
  f32x4 acc[4][4] = {};
  for (int kt = 0; kt < K; kt += 64) {
    #pragma unroll
    for (int i = 0; i < 4; ++i) {
      const int flat = i * 2048 + tid * 8;
      const int r = flat >> 6, cc = flat & 63;
      const int wcc = ((cc >> 3) ^ (r & 7)) << 3;
      const float* g = Af + (row0 + r) * (long)K + kt + cc;
      float4 f0 = *(const float4*)g; float4 f1 = *(const float4*)(g + 4);
      bf16x8 v;
      v[0]=(__bf16)f0.x; v[1]=(__bf16)f0.y; v[2]=(__bf16)f0.z; v[3]=(__bf16)f0.w;
      v[4]=(__bf16)f1.x; v[5]=(__bf16)f1.y; v[6]=(__bf16)f1.z; v[7]=(__bf16)f1.w;
      *(bf16x8*)(As + r * 64 + wcc) = v;
    }
    #pragma unroll
    for (int i = 0; i < 4; ++i) {
      const int flat = i * 2048 + tid * 8;
      const int r = flat >> 6, cc = flat & 63;
      const int wcc = ((cc >> 3) ^ (r & 7)) << 3;
      const long grow = col0 + r;
      const int z = zp[grow];
      const int* g = Bi + grow * (long)K + kt + cc;
      int4 a = *(const int4*)g; int4 b = *(const int4*)(g + 4);
      bf16x8 v;
      v[0]=(__bf16)(float)(a.x-z); v[1]=(__bf16)(float)(a.y-z);
      v[2]=(__bf16)(float)(a.z-z); v[3]=(__bf16)(float)(a.w-z);
      v[4]=(__bf16)(float)(b.x-z); v[5]=(__bf16)(float)(b.y-z);
      v[6]=(__bf16)(float)(b.z-z); v[7]=(__bf16)(float)(b.w-z);
      *(bf16x8*)(Bs + r * 64 + wcc) = v;
    }
    __syncthreads();
    #pragma unroll
    for (int kk = 0; kk < 2; ++kk) {
      bf16x8 af[4], bfr[4];
      const int rs = lane & 15, ks = kk * 4 + (lane >> 4);
      const int rd = (ks ^ (lane & 7)) << 3;
      #pragma unroll
      for (int m = 0; m < 4; ++m) af[m] = *(const bf16x8*)(As + (wr*64 + m*16 + rs)*64 + rd);
      #pragma unroll
      for (int n = 0; n < 4; ++n) bfr[n] = *(const bf16x8*)(Bs + (wc*64 + n*16 + rs)*64 + rd);
      #pragma unroll
      for (int m = 0; m < 4; ++m)
        #pragma unroll
        for (int n = 0; n < 4; ++n)
          acc[m][n] = __builtin_amdgcn_mfma_f32_16x16x32_bf16(af[m], bfr[n], acc[m][n], 0, 0, 0);
    }
    __syncthreads();
  }
  #pragma unroll
  for (int m = 0; m < 4; ++m) {
    const long grow = row0 + wr * 64 + m * 16 + ((lane >> 4) << 2);
    #pragma unroll
    for (int n = 0; n < 4; ++n) {
      const long gcol = col0 + wc * 64 + n * 16 + (lane & 15);
      const float s = scale[gcol], bb2 = bias[gcol];
      float* o = C + grow * (long)N + gcol;
      #pragma unroll
      for (int j = 0; j < 4; ++j) o[(long)j * N] = acc[m][n][j] * s + bb2;
    }
  }
}

extern "C" void kernel_launch(void* const* d_in, const int* in_sizes, int n_in,
                              void* d_out, int out_size, void* d_ws, size_t ws_size,
                              hipStream_t stream) {
  const float* x    = (const float*)d_in[0];
  const int*   wint = (const int*)d_in[1];
  const float* wsc  = (const float*)d_in[2];
  const int*   wzp  = (const int*)d_in[3];
  const float* bias = (const float*)d_in[4];
  float* out = (float*)d_out;

  const int N = in_sizes[4];            // 16384 (OUT)
  const int K = in_sizes[1] / N;        // 4096  (IN)
  const int M = in_sizes[0] / K;        // 8192  (B*S)

  const size_t xqb = (size_t)M * K;             // int8 x
  const size_t wqb = (size_t)N * K;             // int8 w
  const size_t sxb = (size_t)M * sizeof(float);
  const size_t rsb = (size_t)M * sizeof(int);
  const int NT = K / BK;

  if (ws_size >= xqb + wqb + sxb + rsb && (M % BM) == 0 && (N % BN) == 0 &&
      (K % BK) == 0 && (K % 4096) == 0 && NT >= 6 && (NT % 2) == 0) {
    signed char* xq = (signed char*)d_ws;
    signed char* wq = xq + xqb;
    float* sx  = (float*)(wq + wqb);
    int* rsum  = (int*)((char*)sx + sxb);
    quant_x<<<M, 256, 0, stream>>>(x, xq, sx, rsum, K);
    conv_w<<<2048, 256, 0, stream>>>(wint, wzp, wq, K, (long)N * K);
    const int grid = (M / BM) * (N / BN); // 32 * 64 = 2048
    qlin_gemm_i8<<<grid, THREADS, 0, stream>>>(xq, wq, sx, rsum, wzp, wsc, bias,
                                               out, M, N, K);
  } else {
    const int grid = (M / 128) * (N / 128);
    qlin_gemm_small<<<grid, 256, 0, stream>>>(x, wint, wzp, wsc, bias, out, M, N, K);
  }
}

// Round 13
// 702.517 us; speedup vs baseline: 1.7410x; 1.0179x over previous
//
#include <hip/hip_runtime.h>
#include <hip/hip_bf16.h>

typedef __bf16 bf16x8 __attribute__((ext_vector_type(8)));
typedef float  f32x4  __attribute__((ext_vector_type(4)));
typedef int    i32x4  __attribute__((ext_vector_type(4)));

#define BM 256
#define BN 256
#define BK 128          // int8 K-tile; rows are 128 B -> same swizzle as bf16
#define THREADS 512

__device__ __forceinline__ void gload_lds16(const void* g, void* l) {
  __builtin_amdgcn_global_load_lds(
      (const __attribute__((address_space(1))) void*)g,
      (__attribute__((address_space(3))) void*)l, 16, 0, 0);
}

// Bare counted waits (round-6 lesson: ":::memory" clobber => conservative
// vmcnt(0) drain). Ordering vs C++ code pinned with sched_barrier(0).
template<int N> __device__ __forceinline__ void vmwait() {
  if constexpr (N == 0)      asm volatile("s_waitcnt vmcnt(0)");
  else if constexpr (N == 8) asm volatile("s_waitcnt vmcnt(8)");
}

__device__ __forceinline__ void tile_barrier() {
  __builtin_amdgcn_sched_barrier(0);
  asm volatile("s_barrier");
  __builtin_amdgcn_sched_barrier(0);
}

// ---- per-row x quantization: sx = rowmax/127, q = rne(x/sx), rowsum = sum q ----
__global__ __launch_bounds__(256)
void quant_x(const float* __restrict__ x, signed char* __restrict__ xq,
             float* __restrict__ sx, int* __restrict__ rowsum, int K) {
  const int row = blockIdx.x, tid = threadIdx.x;
  const int wave = tid >> 6, lane = tid & 63;
  const float* xr = x + (long)row * K;
  __shared__ float smax[4];
  __shared__ int   ssum[4];

  float amax = 0.f;
  for (int i = tid * 16; i < K; i += 256 * 16) {
    #pragma unroll
    for (int j = 0; j < 4; ++j) {
      float4 v = *(const float4*)(xr + i + j * 4);
      amax = fmaxf(amax, fmaxf(fmaxf(fabsf(v.x), fabsf(v.y)),
                               fmaxf(fabsf(v.z), fabsf(v.w))));
    }
  }
  #pragma unroll
  for (int m = 32; m >= 1; m >>= 1) amax = fmaxf(amax, __shfl_xor(amax, m));
  if (lane == 0) smax[wave] = amax;
  __syncthreads();
  const float m4 = fmaxf(fmaxf(smax[0], smax[1]), fmaxf(smax[2], smax[3]));
  const float scale = (m4 > 0.f) ? (m4 / 127.f) : 1.f;
  const float inv   = (m4 > 0.f) ? (127.f / m4) : 0.f;

  int lsum = 0;
  for (int i = tid * 16; i < K; i += 256 * 16) {
    union { signed char c[16]; int4 v; } u;
    #pragma unroll
    for (int j = 0; j < 4; ++j) {
      float4 v = *(const float4*)(xr + i + j * 4);
      int q0 = __float2int_rn(v.x * inv), q1 = __float2int_rn(v.y * inv);
      int q2 = __float2int_rn(v.z * inv), q3 = __float2int_rn(v.w * inv);
      u.c[j*4+0] = (signed char)q0; u.c[j*4+1] = (signed char)q1;
      u.c[j*4+2] = (signed char)q2; u.c[j*4+3] = (signed char)q3;
      lsum += q0 + q1 + q2 + q3;
    }
    *(int4*)(xq + (long)row * K + i) = u.v;
  }
  #pragma unroll
  for (int m = 32; m >= 1; m >>= 1) lsum += __shfl_xor(lsum, m);
  if (lane == 0) ssum[wave] = lsum;
  __syncthreads();
  if (tid == 0) {
    rowsum[row] = ssum[0] + ssum[1] + ssum[2] + ssum[3];
    sx[row] = scale;
  }
}

// ---- (int32 weight - zp) -> int8 (exact for the symmetric-quant data) ----
__global__ void conv_w(const int* __restrict__ w, const int* __restrict__ zp,
                       signed char* __restrict__ wq, int K, long n) {
  long i0 = ((long)blockIdx.x * blockDim.x + threadIdx.x) * 16;
  long stride = (long)gridDim.x * blockDim.x * 16;
  for (long i = i0; i < n; i += stride) {
    const int z = zp[i / K];
    union { signed char c[16]; int4 v; } u;
    #pragma unroll
    for (int j = 0; j < 4; ++j) {
      int4 a = *(const int4*)(w + i + j * 4);
      int q0 = min(127, max(-128, a.x - z)), q1 = min(127, max(-128, a.y - z));
      int q2 = min(127, max(-128, a.z - z)), q3 = min(127, max(-128, a.w - z));
      u.c[j*4+0] = (signed char)q0; u.c[j*4+1] = (signed char)q1;
      u.c[j*4+2] = (signed char)q2; u.c[j*4+3] = (signed char)q3;
    }
    *(int4*)(wq + i) = u.v;
  }
}

// ====== int8 256x256 GEMM, BK=128, r12 skeleton + T19-pinned interleave ======
// Round-12 ledger: 6140 cy/tile = serial sum of MFMA 2612 + ds_read 2304 +
// ds_write 512 + sync. r11's source-level read/MFMA interleave was NULL
// because LLVM's load-clustering re-hoists the ds_reads into a burst,
// recreating read-burst -> drain -> MFMA-burst. Fix under test (T19):
// sched_group_barrier pins the emitted sequence to
//   [9 DS_READ (bf x8 + af0)] then 15 x [1 DS_READ ; 4 MFMA] + [4 MFMA]
// so each af(f+1) read issues under cluster f's MFMAs; lgkmcnt stays
// counted (1 outstanding), never a drain. Per-step arithmetic: per CU
// 8 waves x 1 read = 96 cy LDS vs 163 cy matrix per SIMD -> read fully
// hidden; predicted tile ~3100 cy.
// Sync per tile unchanged: tile_barrier(i); 8x gload_lds t+2 -> buf b;
// vmcnt(8); tile_barrier(ii). RAW/WAR identical to r12 (audited there).
// Epilogue: out = sx[r]*sw[c]*(acc - zp[c]*rowsum[r]) + bias[c]  (zp exact).
__global__ __launch_bounds__(THREADS, 2)
void qlin_gemm_i8(const signed char* __restrict__ A, const signed char* __restrict__ B,
                  const float* __restrict__ sx, const int* __restrict__ rowsum,
                  const int* __restrict__ zp,
                  const float* __restrict__ scale, const float* __restrict__ bias,
                  float* __restrict__ C, int M, int N, int K) {
  __shared__ alignas(16) signed char As[2][BM * BK];   // 2 x 32 KiB
  __shared__ alignas(16) signed char Bs[2][BN * BK];   // 2 x 32 KiB

  const int tid  = threadIdx.x;
  const int wave = tid >> 6;
  const int lane = tid & 63;
  const int wm = wave >> 2, wn = wave & 3;       // 2x4 waves; per-wave 128x64

  int bid = blockIdx.x, nwg = gridDim.x, swz = bid;
  if ((nwg & 7) == 0) swz = (bid & 7) * (nwg >> 3) + (bid >> 3);
  const int ntn = N / BN;
  const long row0 = (long)(swz / ntn) * BM;
  const long col0 = (long)(swz % ntn) * BN;

  const signed char* Ag = A + row0 * (long)K;
  const signed char* Bg = B + col0 * (long)K;

  // staging: instr covers 8 rows x 128 B; lane l -> row +(l>>3), 16B slot l&7.
  // Pre-swizzled source slot = (l&7) ^ (l>>3)  (same involution as the read).
  const int srow = wave * 8 + (lane >> 3);
  const int kswz = ((lane & 7) ^ (lane >> 3)) * 16;   // bytes == int8 elems

#define STAGE_A(b, c, kt) gload_lds16(Ag + (long)((c)*64 + srow) * K + (kt) + kswz, \
                                      &As[b][(c)*8192 + wave*1024])
#define STAGE_B(b, c, kt) gload_lds16(Bg + (long)((c)*64 + srow) * K + (kt) + kswz, \
                                      &Bs[b][(c)*8192 + wave*1024])
#define STAGE8(b, kt) { STAGE_B(b,0,kt); STAGE_B(b,1,kt); STAGE_B(b,2,kt); STAGE_B(b,3,kt); \
                        STAGE_A(b,0,kt); STAGE_A(b,1,kt); STAGE_A(b,2,kt); STAGE_A(b,3,kt); }

  const int rsel = lane & 15;     // fragment row
  const int ksl  = lane >> 4;     // 0..3 -> k-offset = ksl*16 within K=64 block
  const int lan7 = lane & 7;      // == frag-row & 7 (bases are multiples of 16)

  i32x4 acc[8][4] = {};
  i32x4 bf[4][2];                 // B frags [n][kk], live across one tile

#define AF_READ(bb, m, kk)                                                      \
  (*(const i32x4*)&As[bb][(wm*128 + (m)*16 + rsel)*BK                           \
                          + (((((kk)<<2)+ksl) ^ lan7) << 4)])

#define TILE(bb, STAGES, ENDW)                                                   \
  {                                                                              \
    __builtin_amdgcn_s_setprio(1);                                               \
    _Pragma("unroll")                                                            \
    for (int n = 0; n < 4; ++n)                                                  \
      _Pragma("unroll")                                                          \
      for (int kk = 0; kk < 2; ++kk)                                             \
        bf[n][kk] = *(const i32x4*)&Bs[bb][(wn*64 + n*16 + rsel)*BK              \
                                           + ((((kk<<2)+ksl) ^ lan7) << 4)];     \
    i32x4 afp0, afp1;                                                            \
    afp0 = AF_READ(bb, 0, 0);                                                    \
    __builtin_amdgcn_sched_group_barrier(0x100, 9, 0);  /* bf x8 + af0 */        \
    _Pragma("unroll")                                                            \
    for (int f = 0; f < 16; ++f) {                                               \
      const int m = f & 7, kk = f >> 3;                                          \
      if (f < 15) {                                                              \
        const int m2 = (f + 1) & 7, kk2 = (f + 1) >> 3;                          \
        if (f & 1) afp0 = AF_READ(bb, m2, kk2);                                  \
        else       afp1 = AF_READ(bb, m2, kk2);                                  \
      }                                                                          \
      _Pragma("unroll")                                                          \
      for (int n = 0; n < 4; ++n)                                                \
        acc[m][n] = __builtin_amdgcn_mfma_i32_16x16x64_i8(                       \
            (f & 1) ? afp1 : afp0, bf[n][kk], acc[m][n], 0, 0, 0);               \
      if (f < 15) __builtin_amdgcn_sched_group_barrier(0x100, 1, 0);             \
      __builtin_amdgcn_sched_group_barrier(0x8, 4, 0);                           \
    }                                                                            \
    __builtin_amdgcn_s_setprio(0);                                               \
    tile_barrier();  /* (i) */                                                   \
    STAGES;                                                                      \
    ENDW;                                                                        \
    tile_barrier();  /* (ii) */                                                  \
  }

  const int NT = K / BK;   // 32 for this shape; even, >= 6 (guarded)

  // Prologue: stage tile0 -> buf0, tile1 -> buf1; land tile0 before entering.
  STAGE8(0, 0)
  STAGE8(1, BK)
  vmwait<8>();
  tile_barrier();

  for (int t = 0; t < NT - 3; t += 2) {
    const long kt2 = (long)(t + 2) * BK;
    const long kt3 = (long)(t + 3) * BK;
    TILE(0, STAGE8(0, kt2), vmwait<8>())
    TILE(1, STAGE8(1, kt3), vmwait<8>())
  }
  TILE(0, (void)0, vmwait<0>())      // tile NT-2: drain tile NT-1's batch
  TILE(1, (void)0, (void)0)          // tile NT-1: pure compute
#undef TILE
#undef AF_READ
#undef STAGE8
#undef STAGE_A
#undef STAGE_B

  // Epilogue. C/D layout (dtype-independent, m121-128): col = lane&15,
  // row = (lane>>4)*4 + j.  out = sx*sw*(acc - zp*rowsum) + bias.
  float swv[4], bvv[4]; int zpv[4];
  #pragma unroll
  for (int n = 0; n < 4; ++n) {
    const long gcol = col0 + wn * 64 + n * 16 + rsel;
    swv[n] = scale[gcol];
    bvv[n] = bias[gcol];
    zpv[n] = zp[gcol];
  }
  #pragma unroll
  for (int m = 0; m < 8; ++m) {
    const long growb = row0 + wm * 128 + m * 16 + ksl * 4;
    #pragma unroll
    for (int j = 0; j < 4; ++j) {
      const long grow = growb + j;
      const float sxv = sx[grow];
      const int   rsv = rowsum[grow];
      float* orow = C + grow * (long)N;
      #pragma unroll
      for (int n = 0; n < 4; ++n) {
        const long gcol = col0 + wn * 64 + n * 16 + rsel;
        orow[gcol] = (float)(acc[m][n][j] - zpv[n] * rsv) * (sxv * swv[n]) + bvv[n];
      }
    }
  }
}

// ---- fallback (ws too small / odd shape): reg-staged 128x128 bf16, inline dequant ----
__global__ __launch_bounds__(256)
void qlin_gemm_small(const float* __restrict__ Af, const int* __restrict__ Bi,
                     const int* __restrict__ zp,
                     const float* __restrict__ scale, const float* __restrict__ bias,
                     float* __restrict__ C, int M, int N, int K) {
  __shared__ alignas(16) __bf16 As[128 * 64];
  __shared__ alignas(16) __bf16 Bs[128 * 64];
  const int tid = threadIdx.x, wave = tid >> 6, lane = tid & 63;
  int bid = blockIdx.x, nwg = gridDim.x, swz = bid;
  if ((nwg & 7) == 0) swz = (bid & 7) * (nwg >> 3) + (bid >> 3);
  const int ntn = N / 128;
  const long row0 = (long)(swz / ntn) * 128, col0 = (long)(swz % ntn) * 128;
  const int wr = wave >> 1, wc = wave & 1;
  f32x4 acc[4][4] = {};
  for (int kt = 0; kt < K; kt += 64) {
    #pragma unroll
    for (int i = 0; i < 4; ++i) {
      const int flat = i * 2048 + tid * 8;
      const int r = flat >> 6, cc = flat & 63;
      const int wcc = ((cc >> 3) ^ (r & 7)) << 3;
      const float* g = Af + (row0 + r) * (long)K + kt + cc;
      float4 f0 = *(const float4*)g; float4 f1 = *(const float4*)(g + 4);
      bf16x8 v;
      v[0]=(__bf16)f0.x; v[1]=(__bf16)f0.y; v[2]=(__bf16)f0.z; v[3]=(__bf16)f0.w;
      v[4]=(__bf16)f1.x; v[5]=(__bf16)f1.y; v[6]=(__bf16)f1.z; v[7]=(__bf16)f1.w;
      *(bf16x8*)(As + r * 64 + wcc) = v;
    }
    #pragma unroll
    for (int i = 0; i < 4; ++i) {
      const int flat = i * 2048 + tid * 8;
      const int r = flat >> 6, cc = flat & 63;
      const int wcc = ((cc >> 3) ^ (r & 7)) << 3;
      const long grow = col0 + r;
      const int z = zp[grow];
      const int* g = Bi + grow * (long)K + kt + cc;
      int4 a = *(const int4*)g; int4 b = *(const int4*)(g + 4);
      bf16x8 v;
      v[0]=(__bf16)(float)(a.x-z); v[1]=(__bf16)(float)(a.y-z);
      v[2]=(__bf16)(float)(a.z-z); v[3]=(__bf16)(float)(a.w-z);
      v[4]=(__bf16)(float)(b.x-z); v[5]=(__bf16)(float)(b.y-z);
      v[6]=(__bf16)(float)(b.z-z); v[7]=(__bf16)(float)(b.w-z);
      *(bf16x8*)(Bs + r * 64 + wcc) = v;
    }
    __syncthreads();
    #pragma unroll
    for (int kk = 0; kk < 2; ++kk) {
      bf16x8 af[4], bfr[4];
      const int rs = lane & 15, ks = kk * 4 + (lane >> 4);
      const int rd = (ks ^ (lane & 7)) << 3;
      #pragma unroll
      for (int m = 0; m < 4; ++m) af[m] = *(const bf16x8*)(As + (wr*64 + m*16 + rs)*64 + rd);
      #pragma unroll
      for (int n = 0; n < 4; ++n) bfr[n] = *(const bf16x8*)(Bs + (wc*64 + n*16 + rs)*64 + rd);
      #pragma unroll
      for (int m = 0; m < 4; ++m)
        #pragma unroll
        for (int n = 0; n < 4; ++n)
          acc[m][n] = __builtin_amdgcn_mfma_f32_16x16x32_bf16(af[m], bfr[n], acc[m][n], 0, 0, 0);
    }
    __syncthreads();
  }
  #pragma unroll
  for (int m = 0; m < 4; ++m) {
    const long grow = row0 + wr * 64 + m * 16 + ((lane >> 4) << 2);
    #pragma unroll
    for (int n = 0; n < 4; ++n) {
      const long gcol = col0 + wc * 64 + n * 16 + (lane & 15);
      const float s = scale[gcol], bb2 = bias[gcol];
      float* o = C + grow * (long)N + gcol;
      #pragma unroll
      for (int j = 0; j < 4; ++j) o[(long)j * N] = acc[m][n][j] * s + bb2;
    }
  }
}

extern "C" void kernel_launch(void* const* d_in, const int* in_sizes, int n_in,
                              void* d_out, int out_size, void* d_ws, size_t ws_size,
                              hipStream_t stream) {
  const float* x    = (const float*)d_in[0];
  const int*   wint = (const int*)d_in[1];
  const float* wsc  = (const float*)d_in[2];
  const int*   wzp  = (const int*)d_in[3];
  const float* bias = (const float*)d_in[4];
  float* out = (float*)d_out;

  const int N = in_sizes[4];            // 16384 (OUT)
  const int K = in_sizes[1] / N;        // 4096  (IN)
  const int M = in_sizes[0] / K;        // 8192  (B*S)

  const size_t xqb = (size_t)M * K;             // int8 x
  const size_t wqb = (size_t)N * K;             // int8 w
  const size_t sxb = (size_t)M * sizeof(float);
  const size_t rsb = (size_t)M * sizeof(int);
  const int NT = K / BK;

  if (ws_size >= xqb + wqb + sxb + rsb && (M % BM) == 0 && (N % BN) == 0 &&
      (K % BK) == 0 && (K % 4096) == 0 && NT >= 6 && (NT % 2) == 0) {
    signed char* xq = (signed char*)d_ws;
    signed char* wq = xq + xqb;
    float* sx  = (float*)(wq + wqb);
    int* rsum  = (int*)((char*)sx + sxb);
    quant_x<<<M, 256, 0, stream>>>(x, xq, sx, rsum, K);
    conv_w<<<2048, 256, 0, stream>>>(wint, wzp, wq, K, (long)N * K);
    const int grid = (M / BM) * (N / BN); // 32 * 64 = 2048
    qlin_gemm_i8<<<grid, THREADS, 0, stream>>>(xq, wq, sx, rsum, wzp, wsc, bias,
                                               out, M, N, K);
  } else {
    const int grid = (M / 128) * (N / 128);
    qlin_gemm_small<<<grid, 256, 0, stream>>>(x, wint, wzp, wsc, bias, out, M, N, K);
  }
}